// Round 1
// baseline (9314.684 us; speedup 1.0000x reference)
//
#include <hip/hip_runtime.h>
#include <math.h>

#define NU 20000
#define NI 20000
#define D  64
#define L  50

// ---------------------------------------------------------------------------
// K1: Y[r][d] = sum_k X[r][k] * W[d][k]        (X @ W.T), W is [64][64]
// ---------------------------------------------------------------------------
__global__ __launch_bounds__(256) void hid_kernel(const float* __restrict__ X,
                                                  const float* __restrict__ W,
                                                  float* __restrict__ Y, int N)
{
    __shared__ float sW[64][65];   // padded: bank (d*65+k)%32 = (d+k)%32
    int tid = threadIdx.x;
    for (int i = tid; i < 64 * 64; i += 256) sW[i >> 6][i & 63] = W[i];
    __syncthreads();
    int r = blockIdx.x * 4 + (tid >> 6);
    int d = tid & 63;
    if (r >= N) return;
    const float* x = X + r * 64;
    float acc = 0.f;
    #pragma unroll
    for (int k = 0; k < 64; ++k) acc += x[k] * sW[d][k];
    Y[r * 64 + d] = acc;
}

// ---------------------------------------------------------------------------
// K3: out[r][d] = tanh( sum_k U[d][k]*A[r][k] + U[d][64+k]*F[r][k] )
// ---------------------------------------------------------------------------
__global__ __launch_bounds__(256) void upd_kernel(const float* __restrict__ A,
                                                  const float* __restrict__ F,
                                                  const float* __restrict__ U,
                                                  float* __restrict__ out, int N)
{
    __shared__ float sU[64][130];  // (d*130+k)%32 = (2d+k)%32 -> 2-way (free)
    int tid = threadIdx.x;
    for (int i = tid; i < 64 * 128; i += 256) sU[i >> 7][i & 127] = U[i];
    __syncthreads();
    int r = blockIdx.x * 4 + (tid >> 6);
    int d = tid & 63;
    if (r >= N) return;
    const float* a = A + r * 64;
    const float* f = F + r * 64;
    float acc = 0.f;
    #pragma unroll
    for (int k = 0; k < 64; ++k) acc += a[k] * sU[d][k];
    #pragma unroll
    for (int k = 0; k < 64; ++k) acc += f[k] * sU[d][64 + k];
    out[r * 64 + d] = tanhf(acc);
}

// ---------------------------------------------------------------------------
// GRU single direction. Thread g<192 owns row g of Wi and Wh in registers.
// gin: input sequence (sorted order) in LDS.  gst: per-step hidden out.
// rev=false: t = 0..L-1 ;  rev=true: t = L-1..0 (store at t).
// ---------------------------------------------------------------------------
__device__ __forceinline__ void gru_dir(const float* __restrict__ Wi,
                                        const float* __restrict__ Wh,
                                        const float* __restrict__ bi,
                                        const float* __restrict__ bh,
                                        const float (*gin)[64],
                                        float (*gst)[64],
                                        bool rev,
                                        float* tmpA, float* tmpB, float* hbuf,
                                        int tid)
{
    float wi[64], wh[64];
    float bi_v = 0.f, bh_v = 0.f;
    if (tid < 192) {
        const float4* wip = (const float4*)(Wi + tid * 64);
        const float4* whp = (const float4*)(Wh + tid * 64);
        #pragma unroll
        for (int k = 0; k < 16; ++k) {
            float4 a = wip[k];
            wi[4*k] = a.x; wi[4*k+1] = a.y; wi[4*k+2] = a.z; wi[4*k+3] = a.w;
            float4 b = whp[k];
            wh[4*k] = b.x; wh[4*k+1] = b.y; wh[4*k+2] = b.z; wh[4*k+3] = b.w;
        }
        bi_v = bi[tid];
        bh_v = bh[tid];
    }
    if (tid < 64) hbuf[tid] = 0.f;
    float hreg = 0.f;
    __syncthreads();

    for (int s = 0; s < L; ++s) {
        int t = rev ? (L - 1 - s) : s;
        if (tid < 192) {
            const float4* gp = (const float4*)gin[t];
            const float4* hp = (const float4*)hbuf;
            float xa = 0.f, ha = 0.f;
            #pragma unroll
            for (int k = 0; k < 16; ++k) {
                float4 g4 = gp[k];
                float4 h4 = hp[k];
                xa += wi[4*k]*g4.x + wi[4*k+1]*g4.y + wi[4*k+2]*g4.z + wi[4*k+3]*g4.w;
                ha += wh[4*k]*h4.x + wh[4*k+1]*h4.y + wh[4*k+2]*h4.z + wh[4*k+3]*h4.w;
            }
            float xw = xa + bi_v;    // xw already includes bi
            float gh = ha + bh_v;    // gh includes bh
            if (tid < 128) {
                tmpA[tid] = 1.f / (1.f + expf(-(xw + gh)));   // r (g<64), z (64..127)
            } else {
                tmpA[tid]       = gh;   // raw gh_n
                tmpB[tid - 128] = xw;   // raw xw_n
            }
        }
        __syncthreads();
        if (tid < 64) {
            float r  = tmpA[tid];
            float z  = tmpA[64 + tid];
            float nn = tanhf(tmpB[tid] + r * tmpA[128 + tid]);
            float hn = (1.f - z) * nn + z * hreg;
            hreg = hn;
            hbuf[tid]    = hn;
            gst[t][tid]  = hn;
        }
        __syncthreads();
    }
}

// ---------------------------------------------------------------------------
// K2: full mailbox reduce for one node per block.
// ---------------------------------------------------------------------------
__global__ __launch_bounds__(256) void reduce_kernel(
    const float* __restrict__ src_hid,   // [Nsrc][64]
    const float* __restrict__ dst_hid,   // [N][64]
    const int*   __restrict__ nbr_idx,   // [N][L]
    const int*   __restrict__ nbr_time,  // [N][L]
    const float* __restrict__ te,        // [L][64]
    const float* __restrict__ te_k,      // [L][64]
    const float* __restrict__ Wi,        // [2][192][64]
    const float* __restrict__ Wh,        // [2][192][64]
    const float* __restrict__ bi,        // [2][192]
    const float* __restrict__ bh,        // [2][192]
    const float* __restrict__ glin,      // [64][128]
    const float* __restrict__ agg,       // [64][128]
    float* __restrict__ out)             // [N][64]
{
    __shared__ float bufA[L][64];   // gin (sorted mail)  ->  g_out after combine
    __shared__ float bufB[L][64];   // g_b
    __shared__ float bufC[L][64];   // g_f
    __shared__ float tmpA[192];
    __shared__ float tmpB[64];
    __shared__ float hbuf[64];
    __shared__ int   s_tm[L], s_nid[L], s_ord[L], s_are[L];
    __shared__ float s_ev[L];
    __shared__ float s_hid[64];
    __shared__ float s_last[64];
    __shared__ int   s_lasti;

    const int tid  = threadIdx.x;
    const int n    = blockIdx.x;
    const int lane = tid & 63;

    // ---- P0: load idx/time, stable rank, last (= first argmax) ----
    if (tid < L) { s_tm[tid] = nbr_time[n * L + tid]; s_nid[tid] = nbr_idx[n * L + tid]; }
    __syncthreads();
    if (tid < L) {
        int tl = s_tm[tid];
        int rank = 0;
        for (int m = 0; m < L; ++m) {
            int tm = s_tm[m];
            rank += (tm < tl) || (tm == tl && m < tid);
        }
        s_ord[rank] = tid;          // sorted pos -> original slot
        s_are[tid]  = L - 1 - rank; // reversed rank of original slot
    }
    if (tid == 0) {
        int best = 0, bt = s_tm[0];
        for (int m = 1; m < L; ++m) if (s_tm[m] > bt) { bt = s_tm[m]; best = m; }
        s_lasti = best;
    }
    __syncthreads();

    // ---- P1: gather time-sorted mail, and last message ----
    for (int t = tid >> 6; t < L; t += 4) {
        int row = s_nid[s_ord[t]];
        bufA[t][lane] = src_hid[row * 64 + lane];
    }
    if (tid < 64) s_last[tid] = src_hid[s_nid[s_lasti] * 64 + tid];
    __syncthreads();

    // ---- P3: forward GRU (outputs -> bufC), P5: backward GRU (-> bufB) ----
    gru_dir(Wi,            Wh,            bi,        bh,        bufA, bufC, false,
            tmpA, tmpB, hbuf, tid);
    gru_dir(Wi + 192 * 64, Wh + 192 * 64, bi + 192,  bh + 192,  bufA, bufB, true,
            tmpA, tmpB, hbuf, tid);
    __syncthreads();

    // ---- P6: combine  g_out[t][d] = glin[d][:64].gf[t] + glin[d][64:].gb[t] ----
    {
        const int d  = tid & 63;
        const int tg = tid >> 6;
        float ga[64], gb[64];
        const float4* gp = (const float4*)(glin + d * 128);
        #pragma unroll
        for (int k = 0; k < 16; ++k) {
            float4 v = gp[k];
            ga[4*k] = v.x; ga[4*k+1] = v.y; ga[4*k+2] = v.z; ga[4*k+3] = v.w;
        }
        #pragma unroll
        for (int k = 0; k < 16; ++k) {
            float4 v = gp[16 + k];
            gb[4*k] = v.x; gb[4*k+1] = v.y; gb[4*k+2] = v.z; gb[4*k+3] = v.w;
        }
        float res[13];
        int cnt = 0;
        for (int t = tg; t < L; t += 4) {
            const float4* fp = (const float4*)bufC[t];
            const float4* bp = (const float4*)bufB[t];
            float acc = 0.f;
            #pragma unroll
            for (int k = 0; k < 16; ++k) {
                float4 f4 = fp[k];
                float4 b4 = bp[k];
                acc += ga[4*k]*f4.x + ga[4*k+1]*f4.y + ga[4*k+2]*f4.z + ga[4*k+3]*f4.w;
                acc += gb[4*k]*b4.x + gb[4*k+1]*b4.y + gb[4*k+2]*b4.z + gb[4*k+3]*b4.w;
            }
            res[cnt++] = acc;
        }
        __syncthreads();   // everyone done reading bufC/bufB (and bufA gin is dead)
        cnt = 0;
        for (int t = tg; t < L; t += 4) bufA[t][d] = res[cnt++];  // g_out -> bufA
    }
    __syncthreads();

    // ---- P7: attention scores e[l] and softmax ----
    {
        float dh = dst_hid[n * 64 + lane];
        for (int l = tid >> 6; l < L; l += 4) {
            float v = (te[s_are[l] * 64 + lane] + bufA[l][lane]) * dh;
            #pragma unroll
            for (int o = 32; o > 0; o >>= 1) v += __shfl_down(v, o, 64);
            if (lane == 0) s_ev[l] = v * 0.125f;   // / sqrt(64)
        }
    }
    __syncthreads();
    if (tid < 64) {
        float v = (tid < L) ? s_ev[tid] : -INFINITY;
        float m = v;
        #pragma unroll
        for (int o = 32; o > 0; o >>= 1) m = fmaxf(m, __shfl_xor(m, o, 64));
        float ex = (tid < L) ? expf(v - m) : 0.f;
        float s = ex;
        #pragma unroll
        for (int o = 32; o > 0; o >>= 1) s += __shfl_xor(s, o, 64);
        if (tid < L) s_ev[tid] = ex / s;
    }
    __syncthreads();

    // ---- P8: hid[d] = sum_l alpha[l] * (g_out[l][d] + te_k[are[l]][d]) ----
    if (tid < 64) {
        float acc = 0.f;
        for (int l = 0; l < L; ++l) {
            float a = s_ev[l];
            acc += a * (bufA[l][tid] + te_k[s_are[l] * 64 + tid]);
        }
        s_hid[tid] = acc;
    }
    __syncthreads();

    // ---- P9: out[d] = agg[d][:64].hid + agg[d][64:].last_em ----
    if (tid < 64) {
        const float4* ap = (const float4*)(agg + tid * 128);
        const float4* hp = (const float4*)s_hid;
        const float4* lp = (const float4*)s_last;
        float acc = 0.f;
        #pragma unroll
        for (int k = 0; k < 16; ++k) {
            float4 a = ap[k];      float4 h = hp[k];
            acc += a.x*h.x + a.y*h.y + a.z*h.z + a.w*h.w;
        }
        #pragma unroll
        for (int k = 0; k < 16; ++k) {
            float4 a = ap[16 + k]; float4 e = lp[k];
            acc += a.x*e.x + a.y*e.y + a.z*e.z + a.w*e.w;
        }
        out[n * 64 + tid] = acc;
    }
}

// ---------------------------------------------------------------------------
extern "C" void kernel_launch(void* const* d_in, const int* in_sizes, int n_in,
                              void* d_out, int out_size, void* d_ws, size_t ws_size,
                              hipStream_t stream)
{
    const float* user_feat     = (const float*)d_in[0];
    const float* item_feat     = (const float*)d_in[1];
    const int*   item_nbr_idx  = (const int*)d_in[2];
    const int*   item_nbr_time = (const int*)d_in[3];
    const int*   user_nbr_idx  = (const int*)d_in[4];
    const int*   user_nbr_time = (const int*)d_in[5];
    const float* W_user        = (const float*)d_in[6];
    const float* W_item        = (const float*)d_in[7];
    const float* u_te          = (const float*)d_in[8];
    const float* u_te_k        = (const float*)d_in[9];
    const float* i_te          = (const float*)d_in[10];
    const float* i_te_k        = (const float*)d_in[11];
    const float* gru_u_Wi      = (const float*)d_in[12];
    const float* gru_u_Wh      = (const float*)d_in[13];
    const float* gru_u_bi      = (const float*)d_in[14];
    const float* gru_u_bh      = (const float*)d_in[15];
    const float* gru_i_Wi      = (const float*)d_in[16];
    const float* gru_i_Wh      = (const float*)d_in[17];
    const float* gru_i_bi      = (const float*)d_in[18];
    const float* gru_i_bh      = (const float*)d_in[19];
    const float* gru_lin_u     = (const float*)d_in[20];
    const float* gru_lin_i     = (const float*)d_in[21];
    const float* agg_u         = (const float*)d_in[22];
    const float* agg_i         = (const float*)d_in[23];
    const float* upd_u         = (const float*)d_in[24];
    const float* upd_i         = (const float*)d_in[25];

    float* ws       = (float*)d_ws;
    float* user_hid = ws;
    float* item_hid = user_hid + NU * 64;
    float* item_agg = item_hid + NI * 64;
    float* user_agg = item_agg + NI * 64;

    hid_kernel<<<NU / 4, 256, 0, stream>>>(user_feat, W_user, user_hid, NU);
    hid_kernel<<<NI / 4, 256, 0, stream>>>(item_feat, W_item, item_hid, NI);

    // 'by': user -> item, per item node
    reduce_kernel<<<NI, 256, 0, stream>>>(user_hid, item_hid,
        item_nbr_idx, item_nbr_time, i_te, i_te_k,
        gru_i_Wi, gru_i_Wh, gru_i_bi, gru_i_bh, gru_lin_i, agg_i, item_agg);

    // 'pby': item -> user, per user node
    reduce_kernel<<<NU, 256, 0, stream>>>(item_hid, user_hid,
        user_nbr_idx, user_nbr_time, u_te, u_te_k,
        gru_u_Wi, gru_u_Wh, gru_u_bi, gru_u_bh, gru_lin_u, agg_u, user_agg);

    float* out = (float*)d_out;
    upd_kernel<<<NU / 4, 256, 0, stream>>>(user_agg, user_feat, upd_u, out, NU);
    upd_kernel<<<NI / 4, 256, 0, stream>>>(item_agg, item_feat, upd_i, out + NU * 64, NI);
}